// Round 7
// baseline (618.380 us; speedup 1.0000x reference)
//
#include <hip/hip_runtime.h>
#include <hip/hip_bf16.h>
#include <stdint.h>

// ConvNACCell: out[n,co,h,w] = sum_{ci,kh,kw} x[n,ci,h+kh-1,w+kw-1] * W[co,ci,kh,kw]
// W = tanh(W_hat)*sigmoid(M_hat). Implicit GEMM, mfma_f32_16x16x32_bf16.
// Pass 1: x fp32 NCHW -> bf16 NHWC (ws). Pass 2: conv4 — 512-thread blocks
// (8 waves = 2 co-half x 4 rows = 2 waves/SIMD), x in a 10-slot full-row LDS
// ring staged by global_load_lds, A-fragments read directly from global (L2).

#define CH_IN  64
#define CH_OUT 128
#define HW     256

typedef __attribute__((ext_vector_type(8))) short short8;   // 8 bf16
typedef __attribute__((ext_vector_type(4))) float f32x4;

// ws layout (bytes)
#define ZP_BYTE  147456u
#define XB_BYTE  147712u
#define WS_NEED  (147712ull + 134217728ull)

// conv4 LDS ring
#define NSLOT   10
#define SLOT_B  8448          // 528 granules (66 px * 8 g) * 16 B

static __device__ __forceinline__ uint32_t pack_bf16(float a, float b) {
    uint32_t ua = __builtin_bit_cast(uint32_t, a);
    uint32_t ub = __builtin_bit_cast(uint32_t, b);
    ua = (ua + 0x7FFFu + ((ua >> 16) & 1u)) >> 16;
    ub = (ub + 0x7FFFu + ((ub >> 16) & 1u));
    return (ua & 0xFFFFu) | (ub & 0xFFFF0000u);
}

// ---------------------------------------------------------------------------
// Prep: 16x16x32 A-fragment table + zero page.
//   frag[t][ms(8)][s(2)][lane]: elem j = A[co = ms*16 + (lane&15)]
//                                        [ci = s*32 + (lane>>4)*8 + j], tap t.
// ---------------------------------------------------------------------------
__global__ void __launch_bounds__(256) nac_prep16(const float* __restrict__ Wh,
                                                  const float* __restrict__ Mh,
                                                  uint32_t* __restrict__ ws32) {
    if (blockIdx.x == 0 && threadIdx.x < 64) ws32[ZP_BYTE / 4 + threadIdx.x] = 0;

    int f = blockIdx.x * 256 + threadIdx.x;   // 0..9215
    if (f >= 9 * 8 * 2 * 64) return;
    int lane = f & 63;
    int s    = (f >> 6) & 1;
    int ms   = (f >> 7) & 7;
    int t    = f >> 10;
    int co   = ms * 16 + (lane & 15);
    int ci0  = s * 32 + ((lane >> 4) << 3);

    uint32_t pk[4];
#pragma unroll
    for (int j2 = 0; j2 < 4; ++j2) {
        int ci = ci0 + 2 * j2;
        int k0 = ci * 9 + t;
        int k1 = k0 + 9;
        float w0 = tanhf(Wh[co * 576 + k0]);
        float m0 = Mh[co * 576 + k0];
        float w1 = tanhf(Wh[co * 576 + k1]);
        float m1 = Mh[co * 576 + k1];
        float v0 = w0 * (1.0f / (1.0f + expf(-m0)));
        float v1 = w1 * (1.0f / (1.0f + expf(-m1)));
        pk[j2] = pack_bf16(v0, v1);
    }
    int fragidx = ((t * 8 + ms) * 2 + s) * 64 + lane;
    reinterpret_cast<uint4*>(ws32)[fragidx] = make_uint4(pk[0], pk[1], pk[2], pk[3]);
}

// ---------------------------------------------------------------------------
// Convert: x [16,64,256,256] fp32 NCHW -> xb [16,256,256,64] bf16 NHWC.
// ---------------------------------------------------------------------------
__global__ void __launch_bounds__(256) nac_convert(const float* __restrict__ x,
                                                   uint32_t* __restrict__ xb) {
    int bid = blockIdx.x;            // 4096
    int h   = bid & 255;
    int n   = bid >> 8;
    int px  = threadIdx.x;
    const float* xr = x + ((size_t)n * CH_IN * HW + h) * HW + px;
    uint32_t* orow = xb + ((size_t)(n * HW + h) * HW + px) * 32;
#pragma unroll
    for (int g = 0; g < 8; ++g) {
        float v0 = xr[(size_t)(g * 8 + 0) * HW * HW];
        float v1 = xr[(size_t)(g * 8 + 1) * HW * HW];
        float v2 = xr[(size_t)(g * 8 + 2) * HW * HW];
        float v3 = xr[(size_t)(g * 8 + 3) * HW * HW];
        float v4 = xr[(size_t)(g * 8 + 4) * HW * HW];
        float v5 = xr[(size_t)(g * 8 + 5) * HW * HW];
        float v6 = xr[(size_t)(g * 8 + 6) * HW * HW];
        float v7 = xr[(size_t)(g * 8 + 7) * HW * HW];
        uint4 wd;
        wd.x = pack_bf16(v0, v1); wd.y = pack_bf16(v2, v3);
        wd.z = pack_bf16(v4, v5); wd.w = pack_bf16(v6, v7);
        *reinterpret_cast<uint4*>(orow + g * 4) = wd;
    }
}

// ---------------------------------------------------------------------------
// Conv4. Block = 128co x 16h x 64w, 512 threads, 8 waves (wm co-half, wn row).
// LDS ring: 10 slots, each = one input row hh = h0 + L - 1, px 0..65
// (ww = w0-1+px), granule (px,g) stores ci-octet g^(px&7). Staged by
// global_load_lds: 2 overlapping 512-granule passes per row (idempotent
// overlap keeps every wave's 64 dests linear). Chunk c (4 rows): reads
// slots (4c..4c+5)%10, stages (4c+6..4c+9)%10. A-fragments direct from
// global (147 KB table, L2-hot). Wave tile 64co x 64px, mi=ni=4, acc 64 AGPR.
// ---------------------------------------------------------------------------
__global__ void __launch_bounds__(512, 2)
nac_conv4(const uint32_t* __restrict__ xb, const uint32_t* __restrict__ Af,
          float* __restrict__ out, const uint32_t* __restrict__ zp) {
    __shared__ __align__(1024) uint32_t xl[NSLOT * SLOT_B / 4];   // 84,480 B

    unsigned bid = blockIdx.x;
    unsigned idx = (bid & 7u) * 128u + (bid >> 3);   // bijective XCD swizzle
    const int ht = idx & 15;
    const int wt = (idx >> 4) & 3;
    const int n  = idx >> 6;
    const int h0 = ht * 16, w0 = wt * 64;

    const int tid  = threadIdx.x;
    const int lane = tid & 63;
    const int wv   = tid >> 6;      // 0..7
    const int wm   = wv >> 2;       // co half
    const int wn   = wv & 3;        // row within chunk
    const int col  = lane & 15;
    const int row4 = lane >> 4;

    const char* xbn = reinterpret_cast<const char*>(xb) + ((size_t)n << 23);
    const char* lb  = reinterpret_cast<const char*>(xl);

    // One input row -> one ring slot: two overlapping DMA passes (jr 0..511,
    // 16..527). Dest wave-uniform + lane*16 (linear); source per-lane swizzled.
    auto stage_row = [&](int slot, int hh) {
#pragma unroll
        for (int off = 0; off <= 16; off += 16) {
            const int jr = off + tid;            // 0..527
            const int px = jr >> 3;
            const int g  = jr & 7;
            const int ww = w0 - 1 + px;
            const bool v = ((unsigned)hh < 256u) & ((unsigned)ww < 256u);
            const int hc = v ? hh : 0;
            const int wc = v ? ww : 0;
            const uint32_t* src = v
                ? (const uint32_t*)(xbn + ((size_t)(hc * 256 + wc) << 7)
                                        + ((g ^ (px & 7)) << 4))
                : zp;
            __builtin_amdgcn_global_load_lds(
                (const __attribute__((address_space(1))) uint32_t*)src,
                (__attribute__((address_space(3))) uint32_t*)
                    (xl + (slot * SLOT_B + (off + (tid & ~63)) * 16) / 4),
                16, 0, 0);
        }
    };

    // ---- prologue: rows L = 0..5 -> slots 0..5 ----
#pragma unroll
    for (int L = 0; L < 6; ++L) stage_row(L, h0 - 1 + L);
    __syncthreads();

    // per-lane B byte offsets within a slot (pixel term + swizzled granule)
    int boff[2][3];
#pragma unroll
    for (int s = 0; s < 2; ++s)
#pragma unroll
        for (int kw = 0; kw < 3; ++kw) {
            const int p = col + kw;
            boff[s][kw] = p * 128 + (((s * 4 + row4) ^ (p & 7)) << 4);
        }

    const short8* Afr = reinterpret_cast<const short8*>(Af);

    for (int c = 0; c < 4; ++c) {
        // ---- issue next-chunk DMA (lands under this chunk's compute) ----
        if (c < 3) {
#pragma unroll
            for (int r = 0; r < 4; ++r) {
                int sl = 4 * c + 6 + r; if (sl >= NSLOT) sl -= NSLOT;
                stage_row(sl, h0 + 4 * c + 5 + r);
            }
        }

        // ---- compute: wave's output row = h0 + 4c + wn ----
        f32x4 acc[4][4];
#pragma unroll
        for (int mi = 0; mi < 4; ++mi)
#pragma unroll
            for (int ni = 0; ni < 4; ++ni) acc[mi][ni] = (f32x4){0.f, 0.f, 0.f, 0.f};

        int sb = 4 * c + wn; if (sb >= NSLOT) sb -= NSLOT;
#pragma unroll
        for (int kh = 0; kh < 3; ++kh) {
            int sl = sb + kh; if (sl >= NSLOT) sl -= NSLOT;
            const int mb = sl * SLOT_B;
#pragma unroll
            for (int kw = 0; kw < 3; ++kw) {
                const int t = kh * 3 + kw;
#pragma unroll
                for (int s = 0; s < 2; ++s) {
                    const int abase = ((t * 8 + wm * 4) * 2 + s) * 64 + lane;
                    short8 a0 = Afr[abase];          // global, L2-hot
                    short8 a1 = Afr[abase + 128];
                    short8 a2 = Afr[abase + 256];
                    short8 a3 = Afr[abase + 384];
                    const char* bp = lb + mb + boff[s][kw];
                    short8 b0 = *reinterpret_cast<const short8*>(bp);
                    short8 b1 = *reinterpret_cast<const short8*>(bp + 2048);
                    short8 b2 = *reinterpret_cast<const short8*>(bp + 4096);
                    short8 b3 = *reinterpret_cast<const short8*>(bp + 6144);
                    acc[0][0] = __builtin_amdgcn_mfma_f32_16x16x32_bf16(a0, b0, acc[0][0], 0, 0, 0);
                    acc[1][0] = __builtin_amdgcn_mfma_f32_16x16x32_bf16(a1, b0, acc[1][0], 0, 0, 0);
                    acc[2][0] = __builtin_amdgcn_mfma_f32_16x16x32_bf16(a2, b0, acc[2][0], 0, 0, 0);
                    acc[3][0] = __builtin_amdgcn_mfma_f32_16x16x32_bf16(a3, b0, acc[3][0], 0, 0, 0);
                    acc[0][1] = __builtin_amdgcn_mfma_f32_16x16x32_bf16(a0, b1, acc[0][1], 0, 0, 0);
                    acc[1][1] = __builtin_amdgcn_mfma_f32_16x16x32_bf16(a1, b1, acc[1][1], 0, 0, 0);
                    acc[2][1] = __builtin_amdgcn_mfma_f32_16x16x32_bf16(a2, b1, acc[2][1], 0, 0, 0);
                    acc[3][1] = __builtin_amdgcn_mfma_f32_16x16x32_bf16(a3, b1, acc[3][1], 0, 0, 0);
                    acc[0][2] = __builtin_amdgcn_mfma_f32_16x16x32_bf16(a0, b2, acc[0][2], 0, 0, 0);
                    acc[1][2] = __builtin_amdgcn_mfma_f32_16x16x32_bf16(a1, b2, acc[1][2], 0, 0, 0);
                    acc[2][2] = __builtin_amdgcn_mfma_f32_16x16x32_bf16(a2, b2, acc[2][2], 0, 0, 0);
                    acc[3][2] = __builtin_amdgcn_mfma_f32_16x16x32_bf16(a3, b2, acc[3][2], 0, 0, 0);
                    acc[0][3] = __builtin_amdgcn_mfma_f32_16x16x32_bf16(a0, b3, acc[0][3], 0, 0, 0);
                    acc[1][3] = __builtin_amdgcn_mfma_f32_16x16x32_bf16(a1, b3, acc[1][3], 0, 0, 0);
                    acc[2][3] = __builtin_amdgcn_mfma_f32_16x16x32_bf16(a2, b3, acc[2][3], 0, 0, 0);
                    acc[3][3] = __builtin_amdgcn_mfma_f32_16x16x32_bf16(a3, b3, acc[3][3], 0, 0, 0);
                }
            }
        }

        __syncthreads();   // DMA landed + this chunk's LDS reads done

        // ---- store row h0+4c+wn (drains under next chunk's compute) ----
        const int rr = h0 + 4 * c + wn;
        const size_t ob = (size_t)n * CH_OUT * 65536 + (size_t)rr * 256 + w0;
#pragma unroll
        for (int mi = 0; mi < 4; ++mi)
#pragma unroll
            for (int reg = 0; reg < 4; ++reg) {
                const int co = wm * 64 + mi * 16 + row4 * 4 + reg;
                float* op = out + ob + (size_t)co * 65536;
#pragma unroll
                for (int ni = 0; ni < 4; ++ni) op[ni * 16 + col] = acc[mi][ni][reg];
            }
    }
}

// ---------------------------------------------------------------------------
// Fallback (round-1 proven kernel) if ws too small.
// ---------------------------------------------------------------------------
__global__ void __launch_bounds__(256) nac_conv_fb(const float* __restrict__ x,
                                                   const uint32_t* __restrict__ Af,
                                                   float* __restrict__ out) {
    __shared__ uint32_t xl[8 * 272 * 4];
    unsigned bid = blockIdx.x;
    unsigned idx = (bid & 7u) * 1024u + (bid >> 3);
    int ht = idx & 127;
    int wt = (idx >> 7) & 3;
    int n  = idx >> 9;
    int h0 = ht * 2;
    int w0 = wt * 64;
    int tid = threadIdx.x;

    const float* xn = x + (size_t)n * CH_IN * HW * HW;
    for (int it = 0; it < 9; ++it) {
        int task = tid + it * 256;
        if (task < 2176) {
            int r   = task / 544;
            int rem = task - r * 544;
            int pg  = rem / 68;
            int c   = rem - pg * 68;
            int hrow = h0 - 1 + r;
            int w    = w0 - 1 + c;
            float v[8];
            if ((unsigned)hrow < 256u && (unsigned)w < 256u) {
                const float* p = xn + ((size_t)(pg * 8) * HW + hrow) * HW + w;
#pragma unroll
                for (int e = 0; e < 8; ++e) v[e] = p[(size_t)e * HW * HW];
            } else {
#pragma unroll
                for (int e = 0; e < 8; ++e) v[e] = 0.0f;
            }
            uint4 wd;
            wd.x = pack_bf16(v[0], v[1]);
            wd.y = pack_bf16(v[2], v[3]);
            wd.z = pack_bf16(v[4], v[5]);
            wd.w = pack_bf16(v[6], v[7]);
            *reinterpret_cast<uint4*>(&xl[(pg * 272 + r * 68 + c) * 4]) = wd;
        }
    }
    __syncthreads();

    int lane = tid & 63;
    int wv   = tid >> 6;
    int wm   = wv >> 1;
    int wn   = wv & 1;
    int row4 = lane >> 4;
    int col  = lane & 15;

    f32x4 acc[4][4];
#pragma unroll
    for (int mi = 0; mi < 4; ++mi)
#pragma unroll
        for (int ni = 0; ni < 4; ++ni) acc[mi][ni] = (f32x4){0.f, 0.f, 0.f, 0.f};

    const short8* Afr = reinterpret_cast<const short8*>(Af);
    for (int t = 0; t < 9; ++t) {
        int kh = t / 3, kw = t % 3;
        short8 a[2][4];
#pragma unroll
        for (int s = 0; s < 2; ++s)
#pragma unroll
            for (int mi = 0; mi < 4; ++mi)
                a[s][mi] = Afr[((t * 8 + (wm * 4 + mi)) * 2 + s) * 64 + lane];
#pragma unroll
        for (int s = 0; s < 2; ++s) {
            short8 b[4];
#pragma unroll
            for (int ni = 0; ni < 4; ++ni) {
                int pg = s * 4 + row4;
                int pp = (wn + kh) * 68 + ni * 16 + col + kw;
                b[ni] = *reinterpret_cast<const short8*>(&xl[(pg * 272 + pp) * 4]);
            }
#pragma unroll
            for (int mi = 0; mi < 4; ++mi)
#pragma unroll
                for (int ni = 0; ni < 4; ++ni)
                    acc[mi][ni] = __builtin_amdgcn_mfma_f32_16x16x32_bf16(
                        a[s][mi], b[ni], acc[mi][ni], 0, 0, 0);
        }
    }

#pragma unroll
    for (int mi = 0; mi < 4; ++mi) {
#pragma unroll
        for (int reg = 0; reg < 4; ++reg) {
            int co = wm * 64 + mi * 16 + row4 * 4 + reg;
            float* op = out + (((size_t)n * CH_OUT + co) * HW + (h0 + wn)) * HW + w0;
#pragma unroll
            for (int ni = 0; ni < 4; ++ni) op[ni * 16 + col] = acc[mi][ni][reg];
        }
    }
}

extern "C" void kernel_launch(void* const* d_in, const int* in_sizes, int n_in,
                              void* d_out, int out_size, void* d_ws, size_t ws_size,
                              hipStream_t stream) {
    const float* x  = (const float*)d_in[0];
    const float* Wh = (const float*)d_in[1];
    const float* Mh = (const float*)d_in[2];
    float* out = (float*)d_out;
    uint32_t* ws32 = (uint32_t*)d_ws;
    const uint32_t* Af = ws32;
    const uint32_t* zp = ws32 + ZP_BYTE / 4;
    uint32_t* xbuf = ws32 + XB_BYTE / 4;

    nac_prep16<<<36, 256, 0, stream>>>(Wh, Mh, ws32);
    if (ws_size >= WS_NEED) {
        nac_convert<<<4096, 256, 0, stream>>>(x, xbuf);
        nac_conv4<<<1024, 512, 0, stream>>>(xbuf, Af, out, zp);
    } else {
        nac_conv_fb<<<8192, 256, 0, stream>>>(x, Af, out);
    }
}

// Round 8
// 590.931 us; speedup vs baseline: 1.0464x; 1.0464x over previous
//
#include <hip/hip_runtime.h>
#include <hip/hip_bf16.h>
#include <stdint.h>

// ConvNACCell: out[n,co,h,w] = sum_{ci,kh,kw} x[n,ci,h+kh-1,w+kw-1] * W[co,ci,kh,kw]
// W = tanh(W_hat)*sigmoid(M_hat). Implicit GEMM, mfma_f32_16x16x32_bf16.
// Pass 1: x fp32 NCHW -> bf16 NHWC (ws). Pass 2: conv4 — 512-thread blocks
// (8 waves = 2 co-half x 4 rows = 2 waves/SIMD), x in a 10-slot full-row LDS
// ring staged by global_load_lds, A-fragments read directly from global (L2).
// R8 fix vs R7: __launch_bounds__(512,1) — LDS already caps at 1 block/CU;
// the previous min-2-blocks declaration capped regs at 128 and spilled
// ~387 MB each way (measured WRITE 924 MB vs 537 ideal).

#define CH_IN  64
#define CH_OUT 128
#define HW     256

typedef __attribute__((ext_vector_type(8))) short short8;   // 8 bf16
typedef __attribute__((ext_vector_type(4))) float f32x4;

// ws layout (bytes)
#define ZP_BYTE  147456u
#define XB_BYTE  147712u
#define WS_NEED  (147712ull + 134217728ull)

// conv4 LDS ring
#define NSLOT   10
#define SLOT_B  8448          // 528 granules (66 px * 8 g) * 16 B

static __device__ __forceinline__ uint32_t pack_bf16(float a, float b) {
    uint32_t ua = __builtin_bit_cast(uint32_t, a);
    uint32_t ub = __builtin_bit_cast(uint32_t, b);
    ua = (ua + 0x7FFFu + ((ua >> 16) & 1u)) >> 16;
    ub = (ub + 0x7FFFu + ((ub >> 16) & 1u));
    return (ua & 0xFFFFu) | (ub & 0xFFFF0000u);
}

// ---------------------------------------------------------------------------
// Prep: 16x16x32 A-fragment table + zero page.
//   frag[t][ms(8)][s(2)][lane]: elem j = A[co = ms*16 + (lane&15)]
//                                        [ci = s*32 + (lane>>4)*8 + j], tap t.
// ---------------------------------------------------------------------------
__global__ void __launch_bounds__(256) nac_prep16(const float* __restrict__ Wh,
                                                  const float* __restrict__ Mh,
                                                  uint32_t* __restrict__ ws32) {
    if (blockIdx.x == 0 && threadIdx.x < 64) ws32[ZP_BYTE / 4 + threadIdx.x] = 0;

    int f = blockIdx.x * 256 + threadIdx.x;   // 0..9215
    if (f >= 9 * 8 * 2 * 64) return;
    int lane = f & 63;
    int s    = (f >> 6) & 1;
    int ms   = (f >> 7) & 7;
    int t    = f >> 10;
    int co   = ms * 16 + (lane & 15);
    int ci0  = s * 32 + ((lane >> 4) << 3);

    uint32_t pk[4];
#pragma unroll
    for (int j2 = 0; j2 < 4; ++j2) {
        int ci = ci0 + 2 * j2;
        int k0 = ci * 9 + t;
        int k1 = k0 + 9;
        float w0 = tanhf(Wh[co * 576 + k0]);
        float m0 = Mh[co * 576 + k0];
        float w1 = tanhf(Wh[co * 576 + k1]);
        float m1 = Mh[co * 576 + k1];
        float v0 = w0 * (1.0f / (1.0f + expf(-m0)));
        float v1 = w1 * (1.0f / (1.0f + expf(-m1)));
        pk[j2] = pack_bf16(v0, v1);
    }
    int fragidx = ((t * 8 + ms) * 2 + s) * 64 + lane;
    reinterpret_cast<uint4*>(ws32)[fragidx] = make_uint4(pk[0], pk[1], pk[2], pk[3]);
}

// ---------------------------------------------------------------------------
// Convert: x [16,64,256,256] fp32 NCHW -> xb [16,256,256,64] bf16 NHWC.
// ---------------------------------------------------------------------------
__global__ void __launch_bounds__(256) nac_convert(const float* __restrict__ x,
                                                   uint32_t* __restrict__ xb) {
    int bid = blockIdx.x;            // 4096
    int h   = bid & 255;
    int n   = bid >> 8;
    int px  = threadIdx.x;
    const float* xr = x + ((size_t)n * CH_IN * HW + h) * HW + px;
    uint32_t* orow = xb + ((size_t)(n * HW + h) * HW + px) * 32;
#pragma unroll
    for (int g = 0; g < 8; ++g) {
        float v0 = xr[(size_t)(g * 8 + 0) * HW * HW];
        float v1 = xr[(size_t)(g * 8 + 1) * HW * HW];
        float v2 = xr[(size_t)(g * 8 + 2) * HW * HW];
        float v3 = xr[(size_t)(g * 8 + 3) * HW * HW];
        float v4 = xr[(size_t)(g * 8 + 4) * HW * HW];
        float v5 = xr[(size_t)(g * 8 + 5) * HW * HW];
        float v6 = xr[(size_t)(g * 8 + 6) * HW * HW];
        float v7 = xr[(size_t)(g * 8 + 7) * HW * HW];
        uint4 wd;
        wd.x = pack_bf16(v0, v1); wd.y = pack_bf16(v2, v3);
        wd.z = pack_bf16(v4, v5); wd.w = pack_bf16(v6, v7);
        *reinterpret_cast<uint4*>(orow + g * 4) = wd;
    }
}

// ---------------------------------------------------------------------------
// Conv4. Block = 128co x 16h x 64w, 512 threads, 8 waves (wm co-half, wn row).
// LDS ring: 10 slots, each = one input row hh = h0 + L - 1, px 0..65
// (ww = w0-1+px), granule (px,g) stores ci-octet g^(px&7). Staged by
// global_load_lds: 2 overlapping 512-granule passes per row (idempotent
// overlap keeps every wave's 64 dests linear). Chunk c (4 rows): reads
// slots (4c..4c+5)%10, stages (4c+6..4c+9)%10. A-fragments direct from
// global (147 KB table, L2-hot). Wave tile 64co x 64px, mi=ni=4, acc 64 AGPR.
// ---------------------------------------------------------------------------
__global__ void __launch_bounds__(512, 1)
nac_conv4(const uint32_t* __restrict__ xb, const uint32_t* __restrict__ Af,
          float* __restrict__ out, const uint32_t* __restrict__ zp) {
    __shared__ __align__(1024) uint32_t xl[NSLOT * SLOT_B / 4];   // 84,480 B

    unsigned bid = blockIdx.x;
    unsigned idx = (bid & 7u) * 128u + (bid >> 3);   // bijective XCD swizzle
    const int ht = idx & 15;
    const int wt = (idx >> 4) & 3;
    const int n  = idx >> 6;
    const int h0 = ht * 16, w0 = wt * 64;

    const int tid  = threadIdx.x;
    const int lane = tid & 63;
    const int wv   = tid >> 6;      // 0..7
    const int wm   = wv >> 2;       // co half
    const int wn   = wv & 3;        // row within chunk
    const int col  = lane & 15;
    const int row4 = lane >> 4;

    const char* xbn = reinterpret_cast<const char*>(xb) + ((size_t)n << 23);
    const char* lb  = reinterpret_cast<const char*>(xl);

    // One input row -> one ring slot: two overlapping DMA passes (jr 0..511,
    // 16..527). Dest wave-uniform + lane*16 (linear); source per-lane swizzled.
    auto stage_row = [&](int slot, int hh) {
#pragma unroll
        for (int off = 0; off <= 16; off += 16) {
            const int jr = off + tid;            // 0..527
            const int px = jr >> 3;
            const int g  = jr & 7;
            const int ww = w0 - 1 + px;
            const bool v = ((unsigned)hh < 256u) & ((unsigned)ww < 256u);
            const int hc = v ? hh : 0;
            const int wc = v ? ww : 0;
            const uint32_t* src = v
                ? (const uint32_t*)(xbn + ((size_t)(hc * 256 + wc) << 7)
                                        + ((g ^ (px & 7)) << 4))
                : zp;
            __builtin_amdgcn_global_load_lds(
                (const __attribute__((address_space(1))) uint32_t*)src,
                (__attribute__((address_space(3))) uint32_t*)
                    (xl + (slot * SLOT_B + (off + (tid & ~63)) * 16) / 4),
                16, 0, 0);
        }
    };

    // ---- prologue: rows L = 0..5 -> slots 0..5 ----
#pragma unroll
    for (int L = 0; L < 6; ++L) stage_row(L, h0 - 1 + L);
    __syncthreads();

    // per-lane B byte offsets within a slot (pixel term + swizzled granule)
    int boff[2][3];
#pragma unroll
    for (int s = 0; s < 2; ++s)
#pragma unroll
        for (int kw = 0; kw < 3; ++kw) {
            const int p = col + kw;
            boff[s][kw] = p * 128 + (((s * 4 + row4) ^ (p & 7)) << 4);
        }

    const short8* Afr = reinterpret_cast<const short8*>(Af);

    for (int c = 0; c < 4; ++c) {
        // ---- issue next-chunk DMA (lands under this chunk's compute) ----
        if (c < 3) {
#pragma unroll
            for (int r = 0; r < 4; ++r) {
                int sl = 4 * c + 6 + r; if (sl >= NSLOT) sl -= NSLOT;
                stage_row(sl, h0 + 4 * c + 5 + r);
            }
        }

        // ---- compute: wave's output row = h0 + 4c + wn ----
        f32x4 acc[4][4];
#pragma unroll
        for (int mi = 0; mi < 4; ++mi)
#pragma unroll
            for (int ni = 0; ni < 4; ++ni) acc[mi][ni] = (f32x4){0.f, 0.f, 0.f, 0.f};

        int sb = 4 * c + wn; if (sb >= NSLOT) sb -= NSLOT;
#pragma unroll
        for (int kh = 0; kh < 3; ++kh) {
            int sl = sb + kh; if (sl >= NSLOT) sl -= NSLOT;
            const int mb = sl * SLOT_B;
#pragma unroll
            for (int kw = 0; kw < 3; ++kw) {
                const int t = kh * 3 + kw;
#pragma unroll
                for (int s = 0; s < 2; ++s) {
                    const int abase = ((t * 8 + wm * 4) * 2 + s) * 64 + lane;
                    short8 a0 = Afr[abase];          // global, L2-hot
                    short8 a1 = Afr[abase + 128];
                    short8 a2 = Afr[abase + 256];
                    short8 a3 = Afr[abase + 384];
                    const char* bp = lb + mb + boff[s][kw];
                    short8 b0 = *reinterpret_cast<const short8*>(bp);
                    short8 b1 = *reinterpret_cast<const short8*>(bp + 2048);
                    short8 b2 = *reinterpret_cast<const short8*>(bp + 4096);
                    short8 b3 = *reinterpret_cast<const short8*>(bp + 6144);
                    acc[0][0] = __builtin_amdgcn_mfma_f32_16x16x32_bf16(a0, b0, acc[0][0], 0, 0, 0);
                    acc[1][0] = __builtin_amdgcn_mfma_f32_16x16x32_bf16(a1, b0, acc[1][0], 0, 0, 0);
                    acc[2][0] = __builtin_amdgcn_mfma_f32_16x16x32_bf16(a2, b0, acc[2][0], 0, 0, 0);
                    acc[3][0] = __builtin_amdgcn_mfma_f32_16x16x32_bf16(a3, b0, acc[3][0], 0, 0, 0);
                    acc[0][1] = __builtin_amdgcn_mfma_f32_16x16x32_bf16(a0, b1, acc[0][1], 0, 0, 0);
                    acc[1][1] = __builtin_amdgcn_mfma_f32_16x16x32_bf16(a1, b1, acc[1][1], 0, 0, 0);
                    acc[2][1] = __builtin_amdgcn_mfma_f32_16x16x32_bf16(a2, b1, acc[2][1], 0, 0, 0);
                    acc[3][1] = __builtin_amdgcn_mfma_f32_16x16x32_bf16(a3, b1, acc[3][1], 0, 0, 0);
                    acc[0][2] = __builtin_amdgcn_mfma_f32_16x16x32_bf16(a0, b2, acc[0][2], 0, 0, 0);
                    acc[1][2] = __builtin_amdgcn_mfma_f32_16x16x32_bf16(a1, b2, acc[1][2], 0, 0, 0);
                    acc[2][2] = __builtin_amdgcn_mfma_f32_16x16x32_bf16(a2, b2, acc[2][2], 0, 0, 0);
                    acc[3][2] = __builtin_amdgcn_mfma_f32_16x16x32_bf16(a3, b2, acc[3][2], 0, 0, 0);
                    acc[0][3] = __builtin_amdgcn_mfma_f32_16x16x32_bf16(a0, b3, acc[0][3], 0, 0, 0);
                    acc[1][3] = __builtin_amdgcn_mfma_f32_16x16x32_bf16(a1, b3, acc[1][3], 0, 0, 0);
                    acc[2][3] = __builtin_amdgcn_mfma_f32_16x16x32_bf16(a2, b3, acc[2][3], 0, 0, 0);
                    acc[3][3] = __builtin_amdgcn_mfma_f32_16x16x32_bf16(a3, b3, acc[3][3], 0, 0, 0);
                }
            }
        }

        __syncthreads();   // DMA landed + this chunk's LDS reads done

        // ---- store row h0+4c+wn (drains under next chunk's compute) ----
        const int rr = h0 + 4 * c + wn;
        const size_t ob = (size_t)n * CH_OUT * 65536 + (size_t)rr * 256 + w0;
#pragma unroll
        for (int mi = 0; mi < 4; ++mi)
#pragma unroll
            for (int reg = 0; reg < 4; ++reg) {
                const int co = wm * 64 + mi * 16 + row4 * 4 + reg;
                float* op = out + ob + (size_t)co * 65536;
#pragma unroll
                for (int ni = 0; ni < 4; ++ni) op[ni * 16 + col] = acc[mi][ni][reg];
            }
    }
}

// ---------------------------------------------------------------------------
// Fallback (round-1 proven kernel) if ws too small.
// ---------------------------------------------------------------------------
__global__ void __launch_bounds__(256) nac_conv_fb(const float* __restrict__ x,
                                                   const uint32_t* __restrict__ Af,
                                                   float* __restrict__ out) {
    __shared__ uint32_t xl[8 * 272 * 4];
    unsigned bid = blockIdx.x;
    unsigned idx = (bid & 7u) * 1024u + (bid >> 3);
    int ht = idx & 127;
    int wt = (idx >> 7) & 3;
    int n  = idx >> 9;
    int h0 = ht * 2;
    int w0 = wt * 64;
    int tid = threadIdx.x;

    const float* xn = x + (size_t)n * CH_IN * HW * HW;
    for (int it = 0; it < 9; ++it) {
        int task = tid + it * 256;
        if (task < 2176) {
            int r   = task / 544;
            int rem = task - r * 544;
            int pg  = rem / 68;
            int c   = rem - pg * 68;
            int hrow = h0 - 1 + r;
            int w    = w0 - 1 + c;
            float v[8];
            if ((unsigned)hrow < 256u && (unsigned)w < 256u) {
                const float* p = xn + ((size_t)(pg * 8) * HW + hrow) * HW + w;
#pragma unroll
                for (int e = 0; e < 8; ++e) v[e] = p[(size_t)e * HW * HW];
            } else {
#pragma unroll
                for (int e = 0; e < 8; ++e) v[e] = 0.0f;
            }
            uint4 wd;
            wd.x = pack_bf16(v[0], v[1]);
            wd.y = pack_bf16(v[2], v[3]);
            wd.z = pack_bf16(v[4], v[5]);
            wd.w = pack_bf16(v[6], v[7]);
            *reinterpret_cast<uint4*>(&xl[(pg * 272 + r * 68 + c) * 4]) = wd;
        }
    }
    __syncthreads();

    int lane = tid & 63;
    int wv   = tid >> 6;
    int wm   = wv >> 1;
    int wn   = wv & 1;
    int row4 = lane >> 4;
    int col  = lane & 15;

    f32x4 acc[4][4];
#pragma unroll
    for (int mi = 0; mi < 4; ++mi)
#pragma unroll
        for (int ni = 0; ni < 4; ++ni) acc[mi][ni] = (f32x4){0.f, 0.f, 0.f, 0.f};

    const short8* Afr = reinterpret_cast<const short8*>(Af);
    for (int t = 0; t < 9; ++t) {
        int kh = t / 3, kw = t % 3;
        short8 a[2][4];
#pragma unroll
        for (int s = 0; s < 2; ++s)
#pragma unroll
            for (int mi = 0; mi < 4; ++mi)
                a[s][mi] = Afr[((t * 8 + (wm * 4 + mi)) * 2 + s) * 64 + lane];
#pragma unroll
        for (int s = 0; s < 2; ++s) {
            short8 b[4];
#pragma unroll
            for (int ni = 0; ni < 4; ++ni) {
                int pg = s * 4 + row4;
                int pp = (wn + kh) * 68 + ni * 16 + col + kw;
                b[ni] = *reinterpret_cast<const short8*>(&xl[(pg * 272 + pp) * 4]);
            }
#pragma unroll
            for (int mi = 0; mi < 4; ++mi)
#pragma unroll
                for (int ni = 0; ni < 4; ++ni)
                    acc[mi][ni] = __builtin_amdgcn_mfma_f32_16x16x32_bf16(
                        a[s][mi], b[ni], acc[mi][ni], 0, 0, 0);
        }
    }

#pragma unroll
    for (int mi = 0; mi < 4; ++mi) {
#pragma unroll
        for (int reg = 0; reg < 4; ++reg) {
            int co = wm * 64 + mi * 16 + row4 * 4 + reg;
            float* op = out + (((size_t)n * CH_OUT + co) * HW + (h0 + wn)) * HW + w0;
#pragma unroll
            for (int ni = 0; ni < 4; ++ni) op[ni * 16 + col] = acc[mi][ni][reg];
        }
    }
}

extern "C" void kernel_launch(void* const* d_in, const int* in_sizes, int n_in,
                              void* d_out, int out_size, void* d_ws, size_t ws_size,
                              hipStream_t stream) {
    const float* x  = (const float*)d_in[0];
    const float* Wh = (const float*)d_in[1];
    const float* Mh = (const float*)d_in[2];
    float* out = (float*)d_out;
    uint32_t* ws32 = (uint32_t*)d_ws;
    const uint32_t* Af = ws32;
    const uint32_t* zp = ws32 + ZP_BYTE / 4;
    uint32_t* xbuf = ws32 + XB_BYTE / 4;

    nac_prep16<<<36, 256, 0, stream>>>(Wh, Mh, ws32);
    if (ws_size >= WS_NEED) {
        nac_convert<<<4096, 256, 0, stream>>>(x, xbuf);
        nac_conv4<<<1024, 512, 0, stream>>>(xbuf, Af, out, zp);
    } else {
        nac_conv_fb<<<8192, 256, 0, stream>>>(x, Af, out);
    }
}

// Round 9
// 435.527 us; speedup vs baseline: 1.4198x; 1.3568x over previous
//
#include <hip/hip_runtime.h>
#include <hip/hip_bf16.h>
#include <stdint.h>

// ConvNACCell: out[n,co,h,w] = sum_{ci,kh,kw} x[n,ci,h+kh-1,w+kw-1] * W[co,ci,kh,kw]
// W = tanh(W_hat)*sigmoid(M_hat). Implicit GEMM, mfma_f32_16x16x32_bf16.
// Pass 1: x fp32 NCHW -> bf16 NHWC (ws). Pass 2: conv5 — 256-thread blocks
// (the only spill-free codegen config measured: R1/R3 vs R2/R4/R7/R8),
// block = 128co x 4h x 64w, 6 full input rows in LDS via global_load_lds
// (1.5x halo overfetch), serial stage->barrier->compute, TLP from
// 3 blocks/CU (50.7 KB LDS) x 4 waves = 3 waves/SIMD hides the chain.

#define CH_IN  64
#define CH_OUT 128
#define HW     256

typedef __attribute__((ext_vector_type(8))) short short8;   // 8 bf16
typedef __attribute__((ext_vector_type(4))) float f32x4;

// ws layout (bytes)
#define ZP_BYTE  147456u
#define XB_BYTE  147712u
#define WS_NEED  (147712ull + 134217728ull)

#define SLOT_B  8448          // one input row: 528 granules (66 px * 8 g) * 16 B

static __device__ __forceinline__ uint32_t pack_bf16(float a, float b) {
    uint32_t ua = __builtin_bit_cast(uint32_t, a);
    uint32_t ub = __builtin_bit_cast(uint32_t, b);
    ua = (ua + 0x7FFFu + ((ua >> 16) & 1u)) >> 16;
    ub = (ub + 0x7FFFu + ((ub >> 16) & 1u));
    return (ua & 0xFFFFu) | (ub & 0xFFFF0000u);
}

// ---------------------------------------------------------------------------
// Prep: 16x16x32 A-fragment table + zero page.
//   frag[t][ms(8)][s(2)][lane]: elem j = A[co = ms*16 + (lane&15)]
//                                        [ci = s*32 + (lane>>4)*8 + j], tap t.
// ---------------------------------------------------------------------------
__global__ void __launch_bounds__(256) nac_prep16(const float* __restrict__ Wh,
                                                  const float* __restrict__ Mh,
                                                  uint32_t* __restrict__ ws32) {
    if (blockIdx.x == 0 && threadIdx.x < 64) ws32[ZP_BYTE / 4 + threadIdx.x] = 0;

    int f = blockIdx.x * 256 + threadIdx.x;   // 0..9215
    if (f >= 9 * 8 * 2 * 64) return;
    int lane = f & 63;
    int s    = (f >> 6) & 1;
    int ms   = (f >> 7) & 7;
    int t    = f >> 10;
    int co   = ms * 16 + (lane & 15);
    int ci0  = s * 32 + ((lane >> 4) << 3);

    uint32_t pk[4];
#pragma unroll
    for (int j2 = 0; j2 < 4; ++j2) {
        int ci = ci0 + 2 * j2;
        int k0 = ci * 9 + t;
        int k1 = k0 + 9;
        float w0 = tanhf(Wh[co * 576 + k0]);
        float m0 = Mh[co * 576 + k0];
        float w1 = tanhf(Wh[co * 576 + k1]);
        float m1 = Mh[co * 576 + k1];
        float v0 = w0 * (1.0f / (1.0f + expf(-m0)));
        float v1 = w1 * (1.0f / (1.0f + expf(-m1)));
        pk[j2] = pack_bf16(v0, v1);
    }
    int fragidx = ((t * 8 + ms) * 2 + s) * 64 + lane;
    reinterpret_cast<uint4*>(ws32)[fragidx] = make_uint4(pk[0], pk[1], pk[2], pk[3]);
}

// ---------------------------------------------------------------------------
// Convert: x [16,64,256,256] fp32 NCHW -> xb [16,256,256,64] bf16 NHWC.
// ---------------------------------------------------------------------------
__global__ void __launch_bounds__(256) nac_convert(const float* __restrict__ x,
                                                   uint32_t* __restrict__ xb) {
    int bid = blockIdx.x;            // 4096
    int h   = bid & 255;
    int n   = bid >> 8;
    int px  = threadIdx.x;
    const float* xr = x + ((size_t)n * CH_IN * HW + h) * HW + px;
    uint32_t* orow = xb + ((size_t)(n * HW + h) * HW + px) * 32;
#pragma unroll
    for (int g = 0; g < 8; ++g) {
        float v0 = xr[(size_t)(g * 8 + 0) * HW * HW];
        float v1 = xr[(size_t)(g * 8 + 1) * HW * HW];
        float v2 = xr[(size_t)(g * 8 + 2) * HW * HW];
        float v3 = xr[(size_t)(g * 8 + 3) * HW * HW];
        float v4 = xr[(size_t)(g * 8 + 4) * HW * HW];
        float v5 = xr[(size_t)(g * 8 + 5) * HW * HW];
        float v6 = xr[(size_t)(g * 8 + 6) * HW * HW];
        float v7 = xr[(size_t)(g * 8 + 7) * HW * HW];
        uint4 wd;
        wd.x = pack_bf16(v0, v1); wd.y = pack_bf16(v2, v3);
        wd.z = pack_bf16(v4, v5); wd.w = pack_bf16(v6, v7);
        *reinterpret_cast<uint4*>(orow + g * 4) = wd;
    }
}

// ---------------------------------------------------------------------------
// Conv5. Block = 128co x 4h x 64w, 256 threads, 4 waves (wm co-half, wn pair).
// LDS: 6 input rows (hh = h0-1+L, L=0..5), each 66 px x 8 granules of 16B,
// granule (px,g) stores ci-octet g^(px&7) (XOR swizzle, measured 0-conflict).
// Staged entirely by global_load_lds (zero-page for OOB). One barrier.
// Wave computes its 2 rows sequentially (wr = wn*2+r), 4x4 acc per row.
// A-fragments straight from global (L2/L3-resident 147 KB table).
// ---------------------------------------------------------------------------
__global__ void __launch_bounds__(256)
nac_conv5(const uint32_t* __restrict__ xb, const uint32_t* __restrict__ Af,
          float* __restrict__ out, const uint32_t* __restrict__ zp) {
    __shared__ __align__(1024) uint32_t xl[6 * SLOT_B / 4];   // 50,688 B

    unsigned bid = blockIdx.x;
    unsigned idx = (bid & 7u) * 512u + (bid >> 3);   // bijective XCD swizzle
    const int ht = idx & 63;          // consecutive idx -> vertical neighbors
    const int wt = (idx >> 6) & 3;
    const int n  = idx >> 8;
    const int h0 = ht * 4, w0 = wt * 64;

    const int tid  = threadIdx.x;
    const int lane = tid & 63;
    const int wv   = tid >> 6;      // 0..3
    const int wm   = wv >> 1;       // co half
    const int wn   = wv & 1;        // row-pair index
    const int col  = lane & 15;
    const int row4 = lane >> 4;

    const char* xbn = reinterpret_cast<const char*>(xb) + ((size_t)n << 23);
    const char* lb  = reinterpret_cast<const char*>(xl);

    // ---- stage 6 rows: per row, 2 full passes (jr 0..255, 256..511) + tail
    // (jr 512..527, wave 0 lanes 0..15). Dest wave-uniform base + lane*16;
    // source per-lane pre-swizzled (T21 pattern).
#pragma unroll
    for (int L = 0; L < 6; ++L) {
        const int hh = h0 - 1 + L;
#pragma unroll
        for (int pass = 0; pass < 2; ++pass) {
            const int jr = pass * 256 + tid;       // 0..511
            const int px = jr >> 3;
            const int g  = jr & 7;
            const int ww = w0 - 1 + px;
            const bool v = ((unsigned)hh < 256u) & ((unsigned)ww < 256u);
            const uint32_t* src = v
                ? (const uint32_t*)(xbn + ((size_t)(hh * 256 + ww) << 7)
                                        + ((g ^ (px & 7)) << 4))
                : zp;
            __builtin_amdgcn_global_load_lds(
                (const __attribute__((address_space(1))) uint32_t*)src,
                (__attribute__((address_space(3))) uint32_t*)
                    (xl + (L * SLOT_B + (pass * 256 + (tid & ~63)) * 16) / 4),
                16, 0, 0);
        }
        if (tid < 16) {
            const int jr = 512 + tid;              // px 64,65
            const int px = jr >> 3;
            const int g  = jr & 7;
            const int ww = w0 - 1 + px;
            const bool v = ((unsigned)hh < 256u) & ((unsigned)ww < 256u);
            const uint32_t* src = v
                ? (const uint32_t*)(xbn + ((size_t)(hh * 256 + ww) << 7)
                                        + ((g ^ (px & 7)) << 4))
                : zp;
            __builtin_amdgcn_global_lo\
ad_lds(
                (const __attribute__((address_space(1))) uint32_t*)src,
                (__attribute__((address_space(3))) uint32_t*)
                    (xl + (L * SLOT_B + 512 * 16) / 4),
                16, 0, 0);
        }
    }
    __syncthreads();

    // per-lane B byte offsets within a slot (pixel term + swizzled granule)
    int boff[2][3];
#pragma unroll
    for (int s = 0; s < 2; ++s)
#pragma unroll
        for (int kw = 0; kw < 3; ++kw) {
            const int p = col + kw;
            boff[s][kw] = p * 128 + (((s * 4 + row4) ^ (p & 7)) << 4);
        }

    const short8* Afr = reinterpret_cast<const short8*>(Af);

#pragma unroll
    for (int r = 0; r < 2; ++r) {
        const int wr = wn * 2 + r;               // 0..3: this wave's output row

        f32x4 acc[4][4];
#pragma unroll
        for (int mi = 0; mi < 4; ++mi)
#pragma unroll
            for (int ni = 0; ni < 4; ++ni) acc[mi][ni] = (f32x4){0.f, 0.f, 0.f, 0.f};

#pragma unroll
        for (int kh = 0; kh < 3; ++kh) {
            const int mb = (wr + kh) * SLOT_B;   // slot L = wr + kh
#pragma unroll
            for (int kw = 0; kw < 3; ++kw) {
                const int t = kh * 3 + kw;
#pragma unroll
                for (int s = 0; s < 2; ++s) {
                    const int abase = ((t * 8 + wm * 4) * 2 + s) * 64 + lane;
                    short8 a0 = Afr[abase];          // global, L2-hot
                    short8 a1 = Afr[abase + 128];
                    short8 a2 = Afr[abase + 256];
                    short8 a3 = Afr[abase + 384];
                    const char* bp = lb + mb + boff[s][kw];
                    short8 b0 = *reinterpret_cast<const short8*>(bp);
                    short8 b1 = *reinterpret_cast<const short8*>(bp + 2048);
                    short8 b2 = *reinterpret_cast<const short8*>(bp + 4096);
                    short8 b3 = *reinterpret_cast<const short8*>(bp + 6144);
                    acc[0][0] = __builtin_amdgcn_mfma_f32_16x16x32_bf16(a0, b0, acc[0][0], 0, 0, 0);
                    acc[1][0] = __builtin_amdgcn_mfma_f32_16x16x32_bf16(a1, b0, acc[1][0], 0, 0, 0);
                    acc[2][0] = __builtin_amdgcn_mfma_f32_16x16x32_bf16(a2, b0, acc[2][0], 0, 0, 0);
                    acc[3][0] = __builtin_amdgcn_mfma_f32_16x16x32_bf16(a3, b0, acc[3][0], 0, 0, 0);
                    acc[0][1] = __builtin_amdgcn_mfma_f32_16x16x32_bf16(a0, b1, acc[0][1], 0, 0, 0);
                    acc[1][1] = __builtin_amdgcn_mfma_f32_16x16x32_bf16(a1, b1, acc[1][1], 0, 0, 0);
                    acc[2][1] = __builtin_amdgcn_mfma_f32_16x16x32_bf16(a2, b1, acc[2][1], 0, 0, 0);
                    acc[3][1] = __builtin_amdgcn_mfma_f32_16x16x32_bf16(a3, b1, acc[3][1], 0, 0, 0);
                    acc[0][2] = __builtin_amdgcn_mfma_f32_16x16x32_bf16(a0, b2, acc[0][2], 0, 0, 0);
                    acc[1][2] = __builtin_amdgcn_mfma_f32_16x16x32_bf16(a1, b2, acc[1][2], 0, 0, 0);
                    acc[2][2] = __builtin_amdgcn_mfma_f32_16x16x32_bf16(a2, b2, acc[2][2], 0, 0, 0);
                    acc[3][2] = __builtin_amdgcn_mfma_f32_16x16x32_bf16(a3, b2, acc[3][2], 0, 0, 0);
                    acc[0][3] = __builtin_amdgcn_mfma_f32_16x16x32_bf16(a0, b3, acc[0][3], 0, 0, 0);
                    acc[1][3] = __builtin_amdgcn_mfma_f32_16x16x32_bf16(a1, b3, acc[1][3], 0, 0, 0);
                    acc[2][3] = __builtin_amdgcn_mfma_f32_16x16x32_bf16(a2, b3, acc[2][3], 0, 0, 0);
                    acc[3][3] = __builtin_amdgcn_mfma_f32_16x16x32_bf16(a3, b3, acc[3][3], 0, 0, 0);
                }
            }
        }

        // ---- store output row h0+wr ----
        const size_t ob = (size_t)n * CH_OUT * 65536 + (size_t)(h0 + wr) * 256 + w0;
#pragma unroll
        for (int mi = 0; mi < 4; ++mi)
#pragma unroll
            for (int reg = 0; reg < 4; ++reg) {
                const int co = wm * 64 + mi * 16 + row4 * 4 + reg;
                float* op = out + ob + (size_t)co * 65536;
#pragma unroll
                for (int ni = 0; ni < 4; ++ni) op[ni * 16 + col] = acc[mi][ni][reg];
            }
    }
}

// ---------------------------------------------------------------------------
// Fallback (round-1 proven kernel) if ws too small.
// ---------------------------------------------------------------------------
__global__ void __launch_bounds__(256) nac_conv_fb(const float* __restrict__ x,
                                                   const uint32_t* __restrict__ Af,
                                                   float* __restrict__ out) {
    __shared__ uint32_t xl[8 * 272 * 4];
    unsigned bid = blockIdx.x;
    unsigned idx = (bid & 7u) * 1024u + (bid >> 3);
    int ht = idx & 127;
    int wt = (idx >> 7) & 3;
    int n  = idx >> 9;
    int h0 = ht * 2;
    int w0 = wt * 64;
    int tid = threadIdx.x;

    const float* xn = x + (size_t)n * CH_IN * HW * HW;
    for (int it = 0; it < 9; ++it) {
        int task = tid + it * 256;
        if (task < 2176) {
            int r   = task / 544;
            int rem = task - r * 544;
            int pg  = rem / 68;
            int c   = rem - pg * 68;
            int hrow = h0 - 1 + r;
            int w    = w0 - 1 + c;
            float v[8];
            if ((unsigned)hrow < 256u && (unsigned)w < 256u) {
                const float* p = xn + ((size_t)(pg * 8) * HW + hrow) * HW + w;
#pragma unroll
                for (int e = 0; e < 8; ++e) v[e] = p[(size_t)e * HW * HW];
            } else {
#pragma unroll
                for (int e = 0; e < 8; ++e) v[e] = 0.0f;
            }
            uint4 wd;
            wd.x = pack_bf16(v[0], v[1]);
            wd.y = pack_bf16(v[2], v[3]);
            wd.z = pack_bf16(v[4], v[5]);
            wd.w = pack_bf16(v[6], v[7]);
            *reinterpret_cast<uint4*>(&xl[(pg * 272 + r * 68 + c) * 4]) = wd;
        }
    }
    __syncthreads();

    int lane = tid & 63;
    int wv   = tid >> 6;
    int wm   = wv >> 1;
    int wn   = wv & 1;
    int row4 = lane >> 4;
    int col  = lane & 15;

    f32x4 acc[4][4];
#pragma unroll
    for (int mi = 0; mi < 4; ++mi)
#pragma unroll
        for (int ni = 0; ni < 4; ++ni) acc[mi][ni] = (f32x4){0.f, 0.f, 0.f, 0.f};

    const short8* Afr = reinterpret_cast<const short8*>(Af);
    for (int t = 0; t < 9; ++t) {
        int kh = t / 3, kw = t % 3;
        short8 a[2][4];
#pragma unroll
        for (int s = 0; s < 2; ++s)
#pragma unroll
            for (int mi = 0; mi < 4; ++mi)
                a[s][mi] = Afr[((t * 8 + (wm * 4 + mi)) * 2 + s) * 64 + lane];
#pragma unroll
        for (int s = 0; s < 2; ++s) {
            short8 b[4];
#pragma unroll
            for (int ni = 0; ni < 4; ++ni) {
                int pg = s * 4 + row4;
                int pp = (wn + kh) * 68 + ni * 16 + col + kw;
                b[ni] = *reinterpret_cast<const short8*>(&xl[(pg * 272 + pp) * 4]);
            }
#pragma unroll
            for (int mi = 0; mi < 4; ++mi)
#pragma unroll
                for (int ni = 0; ni < 4; ++ni)
                    acc[mi][ni] = __builtin_amdgcn_mfma_f32_16x16x32_bf16(
                        a[s][mi], b[ni], acc[mi][ni], 0, 0, 0);
        }
    }

#pragma unroll
    for (int mi = 0; mi < 4; ++mi) {
#pragma unroll
        for (int reg = 0; reg < 4; ++reg) {
            int co = wm * 64 + mi * 16 + row4 * 4 + reg;
            float* op = out + (((size_t)n * CH_OUT + co) * HW + (h0 + wn)) * HW + w0;
#pragma unroll
            for (int ni = 0; ni < 4; ++ni) op[ni * 16 + col] = acc[mi][ni][reg];
        }
    }
}

extern "C" void kernel_launch(void* const* d_in, const int* in_sizes, int n_in,
                              void* d_out, int out_size, void* d_ws, size_t ws_size,
                              hipStream_t stream) {
    const float* x  = (const float*)d_in[0];
    const float* Wh = (const float*)d_in[1];
    const float* Mh = (const float*)d_in[2];
    float* out = (float*)d_out;
    uint32_t* ws32 = (uint32_t*)d_ws;
    const uint32_t* Af = ws32;
    const uint32_t* zp = ws32 + ZP_BYTE / 4;
    uint32_t* xbuf = ws32 + XB_BYTE / 4;

    nac_prep16<<<36, 256, 0, stream>>>(Wh, Mh, ws32);
    if (ws_size >= WS_NEED) {
        nac_convert<<<4096, 256, 0, stream>>>(x, xbuf);
        nac_conv5<<<4096, 256, 0, stream>>>(xbuf, Af, out, zp);
    } else {
        nac_conv_fb<<<8192, 256, 0, stream>>>(x, Af, out);
    }
}

// Round 10
// 311.585 us; speedup vs baseline: 1.9846x; 1.3978x over previous
//
#include <hip/hip_runtime.h>
#include <hip/hip_bf16.h>
#include <stdint.h>

// ConvNACCell: out[n,co,h,w] = sum_{ci,kh,kw} x[n,ci,h+kh-1,w+kw-1] * W[co,ci,kh,kw]
// W = tanh(W_hat)*sigmoid(M_hat). Implicit GEMM, mfma_f32_16x16x32_bf16.
// Pass 1: x fp32 NCHW -> bf16 NHWC (ws). Pass 2: conv6 —
//   * A-fragments in REGISTERS (144 VGPR/wave, loaded once from L2 table)
//   * LDS = x row-ring only (6 slots, 50.7 KB -> 2 blocks/CU = 2 waves/SIMD)
//   * 256-thread blocks (only spill-free codegen measured across R1-R9)
//   * global_load_lds staging, lookahead-1, XOR-swizzled (0-conflict measured)
// Evidence: conv3 (A-LDS, 1 wave/SIMD) ~255us; A-global variants 305-400us;
// 512-thr variants spill. conv6 removes conv3's occupancy limit while halving
// LDS traffic (4 ds_reads per 8 MFMA).

#define CH_IN  64
#define CH_OUT 128
#define HW     256

typedef __attribute__((ext_vector_type(8))) short short8;   // 8 bf16
typedef __attribute__((ext_vector_type(4))) float f32x4;

// ws layout (bytes)
#define ZP_BYTE  147456u
#define XB_BYTE  147712u
#define WS_NEED  (147712ull + 134217728ull)

#define SLOT_B  8448          // one input row: 528 granules (66 px * 8 g) * 16 B

static __device__ __forceinline__ uint32_t pack_bf16(float a, float b) {
    uint32_t ua = __builtin_bit_cast(uint32_t, a);
    uint32_t ub = __builtin_bit_cast(uint32_t, b);
    ua = (ua + 0x7FFFu + ((ua >> 16) & 1u)) >> 16;
    ub = (ub + 0x7FFFu + ((ub >> 16) & 1u));
    return (ua & 0xFFFFu) | (ub & 0xFFFF0000u);
}

// ---------------------------------------------------------------------------
// Prep: 16x16x32 A-fragment table + zero page.
//   frag[t][ms(8)][s(2)][lane]: elem j = A[co = ms*16 + (lane&15)]
//                                        [ci = s*32 + (lane>>4)*8 + j], tap t.
// ---------------------------------------------------------------------------
__global__ void __launch_bounds__(256) nac_prep16(const float* __restrict__ Wh,
                                                  const float* __restrict__ Mh,
                                                  uint32_t* __restrict__ ws32) {
    if (blockIdx.x == 0 && threadIdx.x < 64) ws32[ZP_BYTE / 4 + threadIdx.x] = 0;

    int f = blockIdx.x * 256 + threadIdx.x;   // 0..9215
    if (f >= 9 * 8 * 2 * 64) return;
    int lane = f & 63;
    int s    = (f >> 6) & 1;
    int ms   = (f >> 7) & 7;
    int t    = f >> 10;
    int co   = ms * 16 + (lane & 15);
    int ci0  = s * 32 + ((lane >> 4) << 3);

    uint32_t pk[4];
#pragma unroll
    for (int j2 = 0; j2 < 4; ++j2) {
        int ci = ci0 + 2 * j2;
        int k0 = ci * 9 + t;
        int k1 = k0 + 9;
        float w0 = tanhf(Wh[co * 576 + k0]);
        float m0 = Mh[co * 576 + k0];
        float w1 = tanhf(Wh[co * 576 + k1]);
        float m1 = Mh[co * 576 + k1];
        float v0 = w0 * (1.0f / (1.0f + expf(-m0)));
        float v1 = w1 * (1.0f / (1.0f + expf(-m1)));
        pk[j2] = pack_bf16(v0, v1);
    }
    int fragidx = ((t * 8 + ms) * 2 + s) * 64 + lane;
    reinterpret_cast<uint4*>(ws32)[fragidx] = make_uint4(pk[0], pk[1], pk[2], pk[3]);
}

// ---------------------------------------------------------------------------
// Convert: x [16,64,256,256] fp32 NCHW -> xb [16,256,256,64] bf16 NHWC.
// ---------------------------------------------------------------------------
__global__ void __launch_bounds__(256) nac_convert(const float* __restrict__ x,
                                                   uint32_t* __restrict__ xb) {
    int bid = blockIdx.x;            // 4096
    int h   = bid & 255;
    int n   = bid >> 8;
    int px  = threadIdx.x;
    const float* xr = x + ((size_t)n * CH_IN * HW + h) * HW + px;
    uint32_t* orow = xb + ((size_t)(n * HW + h) * HW + px) * 32;
#pragma unroll
    for (int g = 0; g < 8; ++g) {
        float v0 = xr[(size_t)(g * 8 + 0) * HW * HW];
        float v1 = xr[(size_t)(g * 8 + 1) * HW * HW];
        float v2 = xr[(size_t)(g * 8 + 2) * HW * HW];
        float v3 = xr[(size_t)(g * 8 + 3) * HW * HW];
        float v4 = xr[(size_t)(g * 8 + 4) * HW * HW];
        float v5 = xr[(size_t)(g * 8 + 5) * HW * HW];
        float v6 = xr[(size_t)(g * 8 + 6) * HW * HW];
        float v7 = xr[(size_t)(g * 8 + 7) * HW * HW];
        uint4 wd;
        wd.x = pack_bf16(v0, v1); wd.y = pack_bf16(v2, v3);
        wd.z = pack_bf16(v4, v5); wd.w = pack_bf16(v6, v7);
        *reinterpret_cast<uint4*>(orow + g * 4) = wd;
    }
}

// ---------------------------------------------------------------------------
// Conv6. Block = 64co x 16h x 64w, 256 threads, 4 waves = (wq co-quarter) x
// (wn row). Wave = 32co (mi=2) x 64px (ni=4), acc 32 AGPR, A slice (36 frags)
// held in 144 VGPRs. LDS ring: 6 slots, slot L%6 = input row hh = h0+L-1
// (66 px x 8 g, granule (px,g) stores ci-octet g^(px&7)). Chunk c (2 rows):
// reads slots (2c..2c+3)%6, stages rows L=2c+4,2c+5 -> slots (2c+4,2c+5)%6
// (always disjoint). One barrier per chunk. Grid 2048 (cosplit adjacent).
// ---------------------------------------------------------------------------
__global__ void __launch_bounds__(256, 2)
nac_conv6(const uint32_t* __restrict__ xb, const uint32_t* __restrict__ Af,
          float* __restrict__ out, const uint32_t* __restrict__ zp) {
    __shared__ __align__(1024) uint32_t xl[6 * SLOT_B / 4];   // 50,688 B

    unsigned bid = blockIdx.x;
    unsigned idx = (bid & 7u) * 256u + (bid >> 3);   // bijective XCD swizzle
    const int cosplit = idx & 1;
    const int ht = (idx >> 1) & 15;
    const int wt = (idx >> 5) & 3;
    const int n  = idx >> 7;
    const int h0 = ht * 16, w0 = wt * 64;

    const int tid  = threadIdx.x;
    const int lane = tid & 63;
    const int wv   = tid >> 6;      // 0..3
    const int wq   = wv >> 1;       // co quarter within the cosplit half
    const int wn   = wv & 1;        // row within chunk
    const int col  = lane & 15;
    const int row4 = lane >> 4;

    const char* xbn = reinterpret_cast<const char*>(xb) + ((size_t)n << 23);
    const char* lb  = reinterpret_cast<const char*>(xl);

    // ---- A slice into registers: 36 frags, coalesced 1KB loads, L2-hot ----
    const short8* Afr = reinterpret_cast<const short8*>(Af);
    short8 areg[9][2][2];
#pragma unroll
    for (int t = 0; t < 9; ++t)
#pragma unroll
        for (int mi = 0; mi < 2; ++mi)
#pragma unroll
            for (int s = 0; s < 2; ++s)
                areg[t][mi][s] =
                    Afr[((t * 8 + cosplit * 4 + wq * 2 + mi) * 2 + s) * 64 + lane];

    // ---- stage one input row into one ring slot (proven conv5 pattern) ----
    auto stage_row = [&](int slot, int hh) {
#pragma unroll
        for (int pass = 0; pass < 2; ++pass) {
            const int jr = pass * 256 + tid;       // 0..511
            const int px = jr >> 3;
            const int g  = jr & 7;
            const int ww = w0 - 1 + px;
            const bool v = ((unsigned)hh < 256u) & ((unsigned)ww < 256u);
            const uint32_t* src = v
                ? (const uint32_t*)(xbn + ((size_t)(hh * 256 + ww) << 7)
                                        + ((g ^ (px & 7)) << 4))
                : zp;
            __builtin_amdgcn_global_load_lds(
                (const __attribute__((address_space(1))) uint32_t*)src,
                (__attribute__((address_space(3))) uint32_t*)
                    (xl + (slot * SLOT_B + (pass * 256 + (tid & ~63)) * 16) / 4),
                16, 0, 0);
        }
        if (tid < 16) {                            // tail granules 512..527
            const int jr = 512 + tid;
            const int px = jr >> 3;
            const int g  = jr & 7;
            const int ww = w0 - 1 + px;
            const bool v = ((unsigned)hh < 256u) & ((unsigned)ww < 256u);
            const uint32_t* src = v
                ? (const uint32_t*)(xbn + ((size_t)(hh * 256 + ww) << 7)
                                        + ((g ^ (px & 7)) << 4))
                : zp;
            __builtin_amdgcn_global_load_lds(
                (const __attribute__((address_space(1))) uint32_t*)src,
                (__attribute__((address_space(3))) uint32_t*)
                    (xl + (slot * SLOT_B + 512 * 16) / 4),
                16, 0, 0);
        }
    };

    // ---- prologue: rows L0..3 (chunk 0 read window) ----
#pragma unroll
    for (int L = 0; L < 4; ++L) stage_row(L, h0 - 1 + L);
    __syncthreads();

    // per-lane B byte offsets within a slot (ni adds 16px = 2048B, px&7 invariant)
    int boff[2][3];
#pragma unroll
    for (int s = 0; s < 2; ++s)
#pragma unroll
        for (int kw = 0; kw < 3; ++kw) {
            const int p = col + kw;
            boff[s][kw] = p * 128 + (((s * 4 + row4) ^ (p & 7)) << 4);
        }

    for (int c = 0; c < 8; ++c) {
        // ---- issue next-chunk rows (land under this chunk's compute) ----
        if (c < 7) {
            int sl0 = (2 * c + 4) % 6;
            int sl1 = (2 * c + 5) % 6;
            stage_row(sl0, h0 + 2 * c + 3);
            stage_row(sl1, h0 + 2 * c + 4);
        }

        // ---- compute output row h0 + 2c + wn ----
        f32x4 acc[2][4];
#pragma unroll
        for (int mi = 0; mi < 2; ++mi)
#pragma unroll
            for (int ni = 0; ni < 4; ++ni) acc[mi][ni] = (f32x4){0.f, 0.f, 0.f, 0.f};

#pragma unroll
        for (int kh = 0; kh < 3; ++kh) {
            int sl = 2 * c + wn + kh; sl -= (sl >= 6) ? 6 : 0; sl -= (sl >= 6) ? 6 : 0;
            const int mb = sl * SLOT_B;
#pragma unroll
            for (int kw = 0; kw < 3; ++kw) {
                const int t = kh * 3 + kw;
#pragma unroll
                for (int s = 0; s < 2; ++s) {
                    const short8 a0 = areg[t][0][s];
                    const short8 a1 = areg[t][1][s];
                    const char* bp = lb + mb + boff[s][kw];
                    short8 b0 = *reinterpret_cast<const short8*>(bp);
                    short8 b1 = *reinterpret_cast<const short8*>(bp + 2048);
                    short8 b2 = *reinterpret_cast<const short8*>(bp + 4096);
                    short8 b3 = *reinterpret_cast<const short8*>(bp + 6144);
                    acc[0][0] = __builtin_amdgcn_mfma_f32_16x16x32_bf16(a0, b0, acc[0][0], 0, 0, 0);
                    acc[1][0] = __builtin_amdgcn_mfma_f32_16x16x32_bf16(a1, b0, acc[1][0], 0, 0, 0);
                    acc[0][1] = __builtin_amdgcn_mfma_f32_16x16x32_bf16(a0, b1, acc[0][1], 0, 0, 0);
                    acc[1][1] = __builtin_amdgcn_mfma_f32_16x16x32_bf16(a1, b1, acc[1][1], 0, 0, 0);
                    acc[0][2] = __builtin_amdgcn_mfma_f32_16x16x32_bf16(a0, b2, acc[0][2], 0, 0, 0);
                    acc[1][2] = __builtin_amdgcn_mfma_f32_16x16x32_bf16(a1, b2, acc[1][2], 0, 0, 0);
                    acc[0][3] = __builtin_amdgcn_mfma_f32_16x16x32_bf16(a0, b3, acc[0][3], 0, 0, 0);
                    acc[1][3] = __builtin_amdgcn_mfma_f32_16x16x32_bf16(a1, b3, acc[1][3], 0, 0, 0);
                }
            }
        }

        __syncthreads();   // staged DMA landed; this chunk's LDS reads done

        // ---- store output row (drains under next chunk's compute) ----
        const int rr = h0 + 2 * c + wn;
        const size_t ob = (size_t)n * CH_OUT * 65536 + (size_t)rr * 256 + w0;
#pragma unroll
        for (int mi = 0; mi < 2; ++mi)
#pragma unroll
            for (int reg = 0; reg < 4; ++reg) {
                const int co = cosplit * 64 + wq * 32 + mi * 16 + row4 * 4 + reg;
                float* op = out + ob + (size_t)co * 65536;
#pragma unroll
                for (int ni = 0; ni < 4; ++ni) op[ni * 16 + col] = acc[mi][ni][reg];
            }
    }
}

// ---------------------------------------------------------------------------
// Fallback (round-1 proven kernel) if ws too small.
// ---------------------------------------------------------------------------
__global__ void __launch_bounds__(256) nac_conv_fb(const float* __restrict__ x,
                                                   const uint32_t* __restrict__ Af,
                                                   float* __restrict__ out) {
    __shared__ uint32_t xl[8 * 272 * 4];
    unsigned bid = blockIdx.x;
    unsigned idx = (bid & 7u) * 1024u + (bid >> 3);
    int ht = idx & 127;
    int wt = (idx >> 7) & 3;
    int n  = idx >> 9;
    int h0 = ht * 2;
    int w0 = wt * 64;
    int tid = threadIdx.x;

    const float* xn = x + (size_t)n * CH_IN * HW * HW;
    for (int it = 0; it < 9; ++it) {
        int task = tid + it * 256;
        if (task < 2176) {
            int r   = task / 544;
            int rem = task - r * 544;
            int pg  = rem / 68;
            int c   = rem - pg * 68;
            int hrow = h0 - 1 + r;
            int w    = w0 - 1 + c;
            float v[8];
            if ((unsigned)hrow < 256u && (unsigned)w < 256u) {
                const float* p = xn + ((size_t)(pg * 8) * HW + hrow) * HW + w;
#pragma unroll
                for (int e = 0; e < 8; ++e) v[e] = p[(size_t)e * HW * HW];
            } else {
#pragma unroll
                for (int e = 0; e < 8; ++e) v[e] = 0.0f;
            }
            uint4 wd;
            wd.x = pack_bf16(v[0], v[1]);
            wd.y = pack_bf16(v[2], v[3]);
            wd.z = pack_bf16(v[4], v[5]);
            wd.w = pack_bf16(v[6], v[7]);
            *reinterpret_cast<uint4*>(&xl[(pg * 272 + r * 68 + c) * 4]) = wd;
        }
    }
    __syncthreads();

    int lane = tid & 63;
    int wv   = tid >> 6;
    int wm   = wv >> 1;
    int wn   = wv & 1;
    int row4 = lane >> 4;
    int col  = lane & 15;

    f32x4 acc[4][4];
#pragma unroll
    for (int mi = 0; mi < 4; ++mi)
#pragma unroll
        for (int ni = 0; ni < 4; ++ni) acc[mi][ni] = (f32x4){0.f, 0.f, 0.f, 0.f};

    const short8* Afr = reinterpret_cast<const short8*>(Af);
    for (int t = 0; t < 9; ++t) {
        int kh = t / 3, kw = t % 3;
        short8 a[2][4];
#pragma unroll
        for (int s = 0; s < 2; ++s)
#pragma unroll
            for (int mi = 0; mi < 4; ++mi)
                a[s][mi] = Afr[((t * 8 + (wm * 4 + mi)) * 2 + s) * 64 + lane];
#pragma unroll
        for (int s = 0; s < 2; ++s) {
            short8 b[4];
#pragma unroll
            for (int ni = 0; ni < 4; ++ni) {
                int pg = s * 4 + row4;
                int pp = (wn + kh) * 68 + ni * 16 + col + kw;
                b[ni] = *reinterpret_cast<const short8*>(&xl[(pg * 272 + pp) * 4]);
            }
#pragma unroll
            for (int mi = 0; mi < 4; ++mi)
#pragma unroll
                for (int ni = 0; ni < 4; ++ni)
                    acc[mi][ni] = __builtin_amdgcn_mfma_f32_16x16x32_bf16(
                        a[s][mi], b[ni], acc[mi][ni], 0, 0, 0);
        }
    }

#pragma unroll
    for (int mi = 0; mi < 4; ++mi) {
#pragma unroll
        for (int reg = 0; reg < 4; ++reg) {
            int co = wm * 64 + mi * 16 + row4 * 4 + reg;
            float* op = out + (((size_t)n * CH_OUT + co) * HW + (h0 + wn)) * HW + w0;
#pragma unroll
            for (int ni = 0; ni < 4; ++ni) op[ni * 16 + col] = acc[mi][ni][reg];
        }
    }
}

extern "C" void kernel_launch(void* const* d_in, const int* in_sizes, int n_in,
                              void* d_out, int out_size, void* d_ws, size_t ws_size,
                              hipStream_t stream) {
    const float* x  = (const float*)d_in[0];
    const float* Wh = (const float*)d_in[1];
    const float* Mh = (const float*)d_in[2];
    float* out = (float*)d_out;
    uint32_t* ws32 = (uint32_t*)d_ws;
    const uint32_t* Af = ws32;
    const uint32_t* zp = ws32 + ZP_BYTE / 4;
    uint32_t* xbuf = ws32 + XB_BYTE / 4;

    nac_prep16<<<36, 256, 0, stream>>>(Wh, Mh, ws32);
    if (ws_size >= WS_NEED) {
        nac_convert<<<4096, 256, 0, stream>>>(x, xbuf);
        nac_conv6<<<2048, 256, 0, stream>>>(xbuf, Af, out, zp);
    } else {
        nac_conv_fb<<<8192, 256, 0, stream>>>(x, Af, out);
    }
}